// Round 7
// baseline (259.751 us; speedup 1.0000x reference)
//
#include <hip/hip_runtime.h>

// ---------------------------------------------------------------------------
// TensorProduct: e3nn-style channelwise tensor product
//   x1: [16384, 1152] f32  (irreps 128x0e + 128x1o + 128x2e)
//   x2: [16384, 16]   f32  (irreps 1x0e + 1x1o + 1x2e + 1x3o)
//   w : [16384, 2176] f32  (17 paths x 128 mul)
//   out:[16384, 9088] f32  (paths sorted by l3)
// CG coefficients are generated entirely at COMPILE TIME (constexpr fp64
// port of the reference Racah + complex->real basis-change math).
//
// Structure: one block per batch row; thread OWNS output float4-chunks.
// K (= CG . x2) is built once per row in 1.1 KB LDS (single barrier); each
// thread then computes and directly stores its float4 chunks (coalesced
// dwordx4, no output staging, no flush phase).
// ---------------------------------------------------------------------------

#define NPATH 17

namespace cgc {

constexpr double FT[16] = {1.,1.,2.,6.,24.,120.,720.,5040.,40320.,362880.,
  3628800.,39916800.,479001600.,6227020800.,87178291200.,1307674368000.};

constexpr double csqrt(double x){
  if (x <= 0.0) return 0.0;
  double g = x > 1.0 ? x : 1.0;
  for (int i=0;i<48;++i) g = 0.5*(g + x/g);
  return g;
}

constexpr double su2cg(int j1,int m1,int j2,int m2,int j3,int m3){
  if (m1+m2 != m3) return 0.0;
  double pref = csqrt((double)(2*j3+1)*FT[j1+j2-j3]*FT[j1-j2+j3]*FT[-j1+j2+j3]/FT[j1+j2+j3+1]);
  pref *= csqrt(FT[j1+m1]*FT[j1-m1]*FT[j2+m2]*FT[j2-m2]*FT[j3+m3]*FT[j3-m3]);
  int lo=0; if (j2-j3-m1>lo) lo=j2-j3-m1; if (j1-j3+m2>lo) lo=j1-j3+m2;
  int hi=j1+j2-j3; if (j1-m1<hi) hi=j1-m1; if (j2+m2<hi) hi=j2+m2;
  double s=0.0;
  for (int k=lo;k<=hi;++k){
    double d = FT[k]*FT[j1+j2-j3-k]*FT[j1-m1-k]*FT[j2+m2-k]*FT[j3-j2+m1+k]*FT[j3-j1-m2+k];
    s += ((k&1)? -1.0:1.0)/d;
  }
  return pref*s;
}

// q-row nonzeros of real<-complex change of basis (e3nn, phased by (-i)^l)
constexpr int qrow(int l, int r, int* cols, double* vr, double* vi){
  const double is2 = 0.70710678118654752440;
  int mp = r - l;
  int n = 0;
  double tr[2]={0,0}, ti[2]={0,0};
  if (mp < 0){ cols[0]=l-mp; tr[0]=is2; ti[0]=0.0; cols[1]=l+mp; tr[1]=0.0; ti[1]=-is2; n=2; }
  else if (mp==0){ cols[0]=l; tr[0]=1.0; ti[0]=0.0; n=1; }
  else { double sg=(mp&1)?-1.0:1.0; cols[0]=l+mp; tr[0]=sg*is2; ti[0]=0.0;
         cols[1]=l-mp; tr[1]=0.0; ti[1]=sg*is2; n=2; }
  int ph = l & 3;   // multiply by (-i)^l
  for (int t=0;t<n;++t){
    double re=tr[t], im=ti[t], nr=0, ni=0;
    if (ph==0){ nr=re; ni=im; } else if (ph==1){ nr=im; ni=-re; }
    else if (ph==2){ nr=-re; ni=-im; } else { nr=-im; ni=re; }
    vr[t]=nr; vi[t]=ni;
  }
  return n;
}

constexpr int PL1[NPATH] = {0,0,0,0, 1,1,1,1,1,1, 2,2,2,2,2,2,2};
constexpr int PL2[NPATH] = {0,1,2,3, 0,1,1,2,2,3, 0,1,1,2,2,3,3};
constexpr int PL3[NPATH] = {0,1,2,3, 1,0,2,1,3,2, 2,1,3,0,2,1,3};
constexpr int CGOFF[NPATH] = {0,1,10,35,84,93,102,147,192,297,402,427,472,577,602,727,832};
constexpr int X2OFF[NPATH] = {0,1,4,9, 0,1,1,4,4,9, 0,1,1,4,4,9,9};
constexpr int KOFF[NPATH]  = {0,4,8,16,24,36,40,56,68,92,108,136,152,188,196,224,240};
constexpr int KN[NPATH]    = {1,3,5,7, 9,3,15,9,21,15, 25,15,35,5,25,15,35};

struct CGTab { float v[1077]; };

constexpr CGTab make_cg(){
  CGTab R{};
  for (int p=0;p<NPATH;++p){
    const int l1=PL1[p], l2=PL2[p], l3=PL3[p];
    const int N1=2*l1+1, N2=2*l2+1, N3=2*l3+1;
    // dense complex-basis CG, cached (243 su2cg evaluations total)
    double cc[245] = {};
    for (int a=0;a<N1;++a) for (int b=0;b<N2;++b){
      int m1=a-l1, m2=b-l2, m3=m1+m2;
      if (m3>=-l3 && m3<=l3)
        cc[(a*N2+b)*N3 + (m3+l3)] = su2cg(l1,m1,l2,m2,l3,m3);
    }
    double re[245]={}, im[245]={};
    for (int i=0;i<N1;++i){
      int ca[2]={}; double ar[2]={}, ai[2]={};
      const int na=qrow(l1,i,ca,ar,ai);
      for (int j=0;j<N2;++j){
        int cb[2]={}; double br[2]={}, bi[2]={};
        const int nb=qrow(l2,j,cb,br,bi);
        for (int k=0;k<N3;++k){
          int cd[2]={}; double dr[2]={}, di[2]={};
          const int nd=qrow(l3,k,cd,dr,di);
          double sr=0, si=0;
          for (int x=0;x<na;++x) for (int y=0;y<nb;++y){
            const double r1=ar[x], i1=-ai[x];   // conj
            const double r2=br[y], i2=-bi[y];   // conj
            const double r12 = r1*r2 - i1*i2;
            const double i12 = r1*i2 + i1*r2;
            for (int z=0;z<nd;++z){
              const double cg = cc[(ca[x]*N2+cb[y])*N3 + cd[z]];
              if (cg != 0.0){
                sr += cg*(r12*dr[z] - i12*di[z]);
                si += cg*(r12*di[z] + i12*dr[z]);
              }
            }
          }
          re[(i*N2+j)*N3+k]=sr; im[(i*N2+j)*N3+k]=si;
        }
      }
    }
    const int n = N1*N2*N3;
    double nr=0, ni=0;
    for (int e=0;e<n;++e){ nr += re[e]*re[e]; ni += im[e]*im[e]; }
    const bool usere = (nr >= ni);
    const double sc = 1.0 / csqrt(usere ? nr : ni);
    for (int e=0;e<n;++e)
      R.v[CGOFF[p]+e] = (float)((usere ? re[e] : im[e]) * sc);
  }
  return R;
}

// per-thread descriptor for the K (= C . x2) contraction, 243 entries
struct EMap { unsigned short cgbase, dst; unsigned char stride, cnt, x2off, pad; };
struct EMaps { EMap m[243]; };
constexpr EMaps make_emaps(){
  EMaps M{};
  int e=0;
  for (int p=0;p<NPATH;++p){
    const int l2=PL2[p], l3=PL3[p];
    const int N2=2*l2+1, N3=2*l3+1;
    for (int rem=0; rem<KN[p]; ++rem, ++e){
      const int i = rem / N3, k = rem % N3;
      M.m[e].cgbase = (unsigned short)(CGOFF[p] + i*N2*N3 + k);
      M.m[e].dst    = (unsigned short)(KOFF[p] + rem);
      M.m[e].stride = (unsigned char)N3;
      M.m[e].cnt    = (unsigned char)N2;
      M.m[e].x2off  = (unsigned char)X2OFF[p];
      M.m[e].pad    = 0;
    }
  }
  return M;
}

} // namespace cgc

__device__ __constant__ cgc::CGTab c_cg  = cgc::make_cg();
__device__ __constant__ cgc::EMaps c_map = cgc::make_emaps();

// ---------------- main kernel ----------------------------------------------

// chunk of 4 consecutive channels, N3==1 path
template<int N1, int KO>
__device__ __forceinline__ float4 chunk_n3_1(int fo, const float* __restrict__ x1f,
                                             const float* __restrict__ wcol, float alpha,
                                             const float* __restrict__ K){
  float kv[N1];
#pragma unroll
  for (int i=0;i<N1;++i) kv[i] = K[KO+i];
  float4 o; float* op = (float*)&o;
#pragma unroll
  for (int t=0;t<4;++t){
    const int u = fo + t;
    float y = 0.f;
#pragma unroll
    for (int i=0;i<N1;++i) y = fmaf(kv[i], x1f[u*N1+i], y);
    op[t] = alpha * wcol[u] * y;
  }
  return o;
}

// chunk spanning <=2 channels, N3 in {3,5,7}
template<int N1, int N3, int KO>
__device__ __forceinline__ float4 chunk_gen(int fo, const float* __restrict__ x1f,
                                            const float* __restrict__ wcol, float alpha,
                                            const float* __restrict__ K){
  const int u0 = fo / N3;
  const int k0 = fo - u0*N3;
  const int u1 = (k0 + 3 >= N3) ? u0 + 1 : u0;
  const float w0 = alpha * wcol[u0];
  const float w1 = alpha * wcol[u1];
  float xa[N1], xb[N1];
#pragma unroll
  for (int i=0;i<N1;++i) xa[i] = x1f[u0*N1+i];
#pragma unroll
  for (int i=0;i<N1;++i) xb[i] = x1f[u1*N1+i];
  float4 o; float* op = (float*)&o;
#pragma unroll
  for (int t=0;t<4;++t){
    const int k = k0 + t;
    const bool c = (k >= N3);
    const int kk = c ? k - N3 : k;
    float y = 0.f;
#pragma unroll
    for (int i=0;i<N1;++i) y = fmaf(K[KO + i*N3 + kk], c ? xb[i] : xa[i], y);
    op[t] = (c ? w1 : w0) * y;
  }
  return o;
}

__global__ __launch_bounds__(256) void tp_main(const float* __restrict__ x1,
                                               const float* __restrict__ x2,
                                               const float* __restrict__ wts,
                                               float* __restrict__ out){
  __shared__ float sK[276];
  const int tid = threadIdx.x;
  const long long b = blockIdx.x;

  // phase 1: K[i,k] = sum_j C[i,j,k] * x2[b,j]  (243 values, one per thread)
  if (tid < 243){
    const cgc::EMap m = c_map.m[tid];
    const float* __restrict__ C  = c_cg.v + m.cgbase;
    const float* __restrict__ xx = x2 + b*16 + m.x2off;
    float acc = 0.f;
    for (int j=0;j<m.cnt;++j) acc = fmaf(C[j*m.stride], xx[j], acc);
    sK[m.dst] = acc;
  }
  __syncthreads();

  const float* __restrict__ x1b = x1 + b*1152;
  const float* __restrict__ wb  = wts + b*2176;
  const float* __restrict__ K   = sK;
  float4* __restrict__ orow     = (float4*)(out + b*9088);

  const float A0=0.08838834764831845f, A1=0.15309310892394863f,
              A2=0.19764235376052372f, A3=0.23385358667337133f;

  // phase 2: each thread computes+stores its float4 chunks (2272 per row)
#pragma unroll 1
  for (int v = tid; v < 2272; v += 256){
    float4 res;
    if (v < 96){                       // l3=0 segment: 3 path-blocks x 32 f4
      const int blk = v >> 5, fo = (v & 31)*4;
      if      (blk == 0) res = chunk_n3_1<1,0  >(fo, x1b+0,   wb+0*128,  A0, K);
      else if (blk == 1) res = chunk_n3_1<3,36 >(fo, x1b+128, wb+5*128,  A0, K);
      else               res = chunk_n3_1<5,188>(fo, x1b+512, wb+13*128, A0, K);
    } else if (v < 576){               // l3=1: 5 path-blocks x 96 f4
      const int vv = v - 96, blk = vv/96, fo = (vv - blk*96)*4;
      switch (blk){
        case 0:  res = chunk_gen<1,3,4  >(fo, x1b+0,   wb+1*128,  A1, K); break;
        case 1:  res = chunk_gen<3,3,24 >(fo, x1b+128, wb+4*128,  A1, K); break;
        case 2:  res = chunk_gen<3,3,56 >(fo, x1b+128, wb+7*128,  A1, K); break;
        case 3:  res = chunk_gen<5,3,136>(fo, x1b+512, wb+11*128, A1, K); break;
        default: res = chunk_gen<5,3,224>(fo, x1b+512, wb+15*128, A1, K); break;
      }
    } else if (v < 1376){              // l3=2: 5 path-blocks x 160 f4
      const int vv = v - 576, blk = vv/160, fo = (vv - blk*160)*4;
      switch (blk){
        case 0:  res = chunk_gen<1,5,8  >(fo, x1b+0,   wb+2*128,  A2, K); break;
        case 1:  res = chunk_gen<3,5,40 >(fo, x1b+128, wb+6*128,  A2, K); break;
        case 2:  res = chunk_gen<3,5,92 >(fo, x1b+128, wb+9*128,  A2, K); break;
        case 3:  res = chunk_gen<5,5,108>(fo, x1b+512, wb+10*128, A2, K); break;
        default: res = chunk_gen<5,5,196>(fo, x1b+512, wb+14*128, A2, K); break;
      }
    } else {                           // l3=3: 4 path-blocks x 224 f4
      const int vv = v - 1376, blk = vv/224, fo = (vv - blk*224)*4;
      switch (blk){
        case 0:  res = chunk_gen<1,7,16 >(fo, x1b+0,   wb+3*128,  A3, K); break;
        case 1:  res = chunk_gen<3,7,68 >(fo, x1b+128, wb+8*128,  A3, K); break;
        case 2:  res = chunk_gen<5,7,152>(fo, x1b+512, wb+12*128, A3, K); break;
        default: res = chunk_gen<5,7,240>(fo, x1b+512, wb+16*128, A3, K); break;
      }
    }
    orow[v] = res;
  }
}

// ---------------- launch ----------------------------------------------------

extern "C" void kernel_launch(void* const* d_in, const int* in_sizes, int n_in,
                              void* d_out, int out_size, void* d_ws, size_t ws_size,
                              hipStream_t stream) {
  const float* x1 = (const float*)d_in[0];
  const float* x2 = (const float*)d_in[1];
  const float* w  = (const float*)d_in[2];
  float* out = (float*)d_out;
  (void)d_ws; (void)ws_size; (void)in_sizes; (void)n_in; (void)out_size;

  tp_main<<<dim3(16384), dim3(256), 0, stream>>>(x1, x2, w, out);
}